// Round 1
// 86.521 us; speedup vs baseline: 1.0333x; 1.0333x over previous
//
#include <hip/hip_runtime.h>
#include <stdint.h>

// Fused 4-bit dequant matvec, ZERO workspace use.
// y[o] = bias[o] + scales[o] * sum_k x[k]*w[k,o] - zeros[o] * sum_k x[k]
//
// Grid: 256 blocks x 512 threads. Each block owns 32 output columns and the
// full K=8192 reduction. x (32 KB) staged once in LDS; qweight (32 MiB) read
// exactly once, coalesced as uint4 (8 rows x 128 B segments per wave).
// In-block split-k: 64 row-groups, reduced via 8 KB LDS.

#define THREADS 512
#define COLS_PER_BLOCK 32          // 8 uint4 chunks of 4 cols
#define ROWS 1024                  // qweight word-rows (K/8)
#define OUTF 8192
#define RG 64                      // row-groups = THREADS/8
#define ITERS (ROWS / RG)          // 16

// Accumulate 8 nibbles of word w against 8 x values (x[r*8+0..7]).
// Nibble j of w is k = r*8 + j. lo = nibbles 0,2,4,6 ; hi = nibbles 1,3,5,7.
// (float)((u >> 8k) & 0xFF) pattern-matches to v_cvt_f32_ubyteN.
__device__ __forceinline__ float dot8(const float4& xa, const float4& xb,
                                      uint32_t w, float acc) {
    uint32_t lo = w & 0x0F0F0F0Fu;
    uint32_t hi = (w >> 4) & 0x0F0F0F0Fu;
    acc = fmaf(xa.x, (float)(lo & 0xFFu),         acc);
    acc = fmaf(xa.y, (float)(hi & 0xFFu),         acc);
    acc = fmaf(xa.z, (float)((lo >> 8) & 0xFFu),  acc);
    acc = fmaf(xa.w, (float)((hi >> 8) & 0xFFu),  acc);
    acc = fmaf(xb.x, (float)((lo >> 16) & 0xFFu), acc);
    acc = fmaf(xb.y, (float)((hi >> 16) & 0xFFu), acc);
    acc = fmaf(xb.z, (float)(lo >> 24),           acc);
    acc = fmaf(xb.w, (float)(hi >> 24),           acc);
    return acc;
}

__global__ __launch_bounds__(THREADS) void qmatvec4_fused(
    const float* __restrict__ x,
    const uint32_t* __restrict__ qw,
    const float* __restrict__ scales,
    const float* __restrict__ zeros,
    const float* __restrict__ bias,
    float* __restrict__ out)
{
    __shared__ float4 xs4[ROWS * 2];              // 32 KB: all of x
    __shared__ float  red[RG][COLS_PER_BLOCK];    // 8 KB: split-k partials
    __shared__ float  wred[THREADS / 64];         // per-wave xsum partials

    const int tid = threadIdx.x;
    const int ck  = tid & 7;                      // uint4 chunk (4 cols)
    const int rg  = tid >> 3;                     // row-group 0..63
    const int c0  = blockIdx.x * COLS_PER_BLOCK;

    // Stage x into LDS: 2048 float4, 4 per thread, coalesced.
    const float4* xg = (const float4*)x;
    #pragma unroll
    for (int i = 0; i < 4; ++i)
        xs4[tid + i * THREADS] = xg[tid + i * THREADS];
    __syncthreads();

    // Main loop: each thread covers 16 word-rows x 4 columns.
    // x LDS reads: 8 distinct rg per wave, addresses 32 B apart ->
    // ds_read_b128 conflict-free (rg0 banks 0-3 ... rg7 banks 28-31).
    const uint4* qv = (const uint4*)qw;
    float a0 = 0.f, a1 = 0.f, a2 = 0.f, a3 = 0.f;
    #pragma unroll
    for (int it = 0; it < ITERS; ++it) {
        const int r = rg + it * RG;
        float4 xa = xs4[r * 2];
        float4 xb = xs4[r * 2 + 1];
        uint4 w = qv[(size_t)r * (OUTF / 4) + (c0 >> 2) + ck];
        a0 = dot8(xa, xb, w.x, a0);
        a1 = dot8(xa, xb, w.y, a1);
        a2 = dot8(xa, xb, w.z, a2);
        a3 = dot8(xa, xb, w.w, a3);
    }

    // Park split-k partials: red[rg][ck*4 .. ck*4+3], 16B-aligned store.
    *(float4*)&red[rg][ck * 4] = make_float4(a0, a1, a2, a3);

    // Block-redundant xsum from LDS-staged x (no cross-block traffic).
    float xs = 0.f;
    #pragma unroll
    for (int i = 0; i < 4; ++i) {
        float4 v = xs4[tid + i * THREADS];
        xs += v.x + v.y + v.z + v.w;
    }
    #pragma unroll
    for (int off = 32; off; off >>= 1)
        xs += __shfl_down(xs, off);               // wave64 reduce
    if ((tid & 63) == 0)
        wred[tid >> 6] = xs;

    __syncthreads();                              // red[] + wred[] visible

    // Epilogue: 32 threads, one output column each.
    if (tid < COLS_PER_BLOCK) {
        float xsum = 0.f;
        #pragma unroll
        for (int wv = 0; wv < THREADS / 64; ++wv)
            xsum += wred[wv];

        float s = 0.f;
        #pragma unroll
        for (int g = 0; g < RG; ++g)
            s += red[g][tid];                     // bank = col -> conflict-free

        const int c = c0 + tid;
        out[c] = fmaf(scales[c], s, bias[c]) - zeros[c] * xsum;
    }
}

extern "C" void kernel_launch(void* const* d_in, const int* in_sizes, int n_in,
                              void* d_out, int out_size, void* d_ws, size_t ws_size,
                              hipStream_t stream) {
    const float*    x      = (const float*)d_in[0];
    const uint32_t* qw     = (const uint32_t*)d_in[1];
    const float*    scales = (const float*)d_in[2];
    const float*    zeros  = (const float*)d_in[3];
    const float*    bias   = (const float*)d_in[4];
    float*          out    = (float*)d_out;
    (void)d_ws; (void)ws_size;                    // workspace intentionally unused

    qmatvec4_fused<<<dim3(OUTF / COLS_PER_BLOCK), THREADS, 0, stream>>>(
        x, qw, scales, zeros, bias, out);
}